// Round 1
// 401.815 us; speedup vs baseline: 1.0000x; 1.0000x over previous
//
#include <hip/hip_runtime.h>
#include <hip/hip_bf16.h>

// out[b,s,f] = sum_e z[e]*W[f,e] + b[f]; z depends only on gate params, so the
// whole (8,8192,1024) output is one 1024-float vector y broadcast over 65536
// rows. Floor for the controllable part: 256 MB of stores ~= 41 us at the
// 6.5 TB/s fill rate the harness's own fillBufferAligned demonstrates.
// Measured 401.8 us total is ~2x164 us of 1-GiB harness poison fills inside
// the timed window + ~60-70 us of our kernels; this version polishes the
// controllable slice toward its floor.
//
// Structure: 2 kernels.
//  A) y_kernel: 256 blocks x 4 rows; each block recomputes the z vector
//     (cheap trig) into LDS once, then dots 4 W rows against it.
//  B) bcast_kernel: register-resident row broadcast, nontemporal store
//     stream, 2048 blocks (8 blocks/CU -> 32 waves/CU max occupancy).

#define E 1024
#define ROWS_PER_Y_BLOCK 4
#define ROWS_PER_BC_BLOCK 32

typedef float f32x4 __attribute__((ext_vector_type(4)));

// ---- Kernel A: y[f] = b[f] + sum_e W[f,e]*z[e], z computed once per block --
__global__ void __launch_bounds__(256)
y_kernel(const float* __restrict__ bs_theta,
         const float* __restrict__ bs_phi,
         const float* __restrict__ phases,
         const float* __restrict__ squeeze_r,
         const float* __restrict__ displacement_r,
         const float* __restrict__ W,
         const float* __restrict__ bias,
         float* __restrict__ y) {
    __shared__ float zs[E];
    __shared__ float sm[ROWS_PER_Y_BLOCK][4];

    // wire-uniform prefix: |0> -> rx(bs_theta) -> ry(bs_phi)
    float h1 = 0.5f * bs_theta[0];
    float c1 = cosf(h1), s1 = sinf(h1);
    float h2 = 0.5f * bs_phi[0];
    float c2 = cosf(h2), s2 = sinf(h2);
    float ar0 = c2 * c1, ai0 = s2 * s1;
    float br0 = s2 * c1, bi0 = -c2 * s1;

    #pragma unroll
    for (int k = 0; k < E / 256; ++k) {
        int e = threadIdx.x + k * 256;
        float ar = ar0, ai = ai0, br = br0, bi = bi0;

        // rz(phases[e])
        float hp = 0.5f * phases[e];
        float pr = cosf(hp), pi = -sinf(hp);
        float nar = ar * pr - ai * pi, nai = ar * pi + ai * pr;
        float nbr = br * pr + bi * pi, nbi = bi * pr - br * pi;
        ar = nar; ai = nai; br = nbr; bi = nbi;

        // ry(squeeze_r[e])
        float hs = 0.5f * squeeze_r[e];
        float cs = cosf(hs), ss = sinf(hs);
        nar = cs * ar - ss * br; nai = cs * ai - ss * bi;
        nbr = ss * ar + cs * br; nbi = ss * ai + cs * bi;
        ar = nar; ai = nai; br = nbr; bi = nbi;

        // rx(displacement_r[e])
        float hd = 0.5f * displacement_r[e];
        float cd = cosf(hd), sd = sinf(hd);
        nar = cd * ar + sd * bi; nai = cd * ai - sd * br;
        nbr = sd * ai + cd * br; nbi = cd * bi - sd * ar;

        // rz(kerr) preserves magnitudes -> skip. <Z> = |a|^2 - |b|^2
        zs[e] = (nar * nar + nai * nai) - (nbr * nbr + nbi * nbi);
    }
    __syncthreads();

    int lane = threadIdx.x & 63, wv = threadIdx.x >> 6;
    f32x4 zv = ((const f32x4*)zs)[threadIdx.x];
    int f0 = blockIdx.x * ROWS_PER_Y_BLOCK;

    #pragma unroll
    for (int r = 0; r < ROWS_PER_Y_BLOCK; ++r) {
        const f32x4* row4 = (const f32x4*)(W + (size_t)(f0 + r) * E);
        f32x4 w = row4[threadIdx.x];
        float p = w.x * zv.x + w.y * zv.y + w.z * zv.z + w.w * zv.w;
        #pragma unroll
        for (int o = 32; o > 0; o >>= 1) p += __shfl_down(p, o, 64);
        if (lane == 0) sm[r][wv] = p;
    }
    __syncthreads();
    if (threadIdx.x < ROWS_PER_Y_BLOCK) {
        int r = threadIdx.x;
        y[f0 + r] = sm[r][0] + sm[r][1] + sm[r][2] + sm[r][3] + bias[f0 + r];
    }
}

// ---- Kernel B: broadcast y over rows; value lives in a register ------------
// Nontemporal dwordx4 stores: pure write stream, no L2 residency needed.
__global__ void __launch_bounds__(256)
bcast_kernel(const f32x4* __restrict__ y4, f32x4* __restrict__ out) {
    f32x4 v = y4[threadIdx.x];                  // 256 thr x float4 = one row
    size_t base = (size_t)blockIdx.x * (ROWS_PER_BC_BLOCK * (E / 4))
                + threadIdx.x;
    #pragma unroll
    for (int r = 0; r < ROWS_PER_BC_BLOCK; ++r)
        __builtin_nontemporal_store(v, out + base + (size_t)r * (E / 4));
}

extern "C" void kernel_launch(void* const* d_in, const int* in_sizes, int n_in,
                              void* d_out, int out_size, void* d_ws, size_t ws_size,
                              hipStream_t stream) {
    const float* bs_theta       = (const float*)d_in[1];
    const float* bs_phi         = (const float*)d_in[2];
    const float* phases         = (const float*)d_in[3];
    const float* squeeze_r      = (const float*)d_in[4];
    const float* displacement_r = (const float*)d_in[5];
    const float* W_combine      = (const float*)d_in[7];
    const float* b_combine      = (const float*)d_in[8];

    float* y = (float*)d_ws;          // E floats

    y_kernel<<<E / ROWS_PER_Y_BLOCK, 256, 0, stream>>>(
        bs_theta, bs_phi, phases, squeeze_r, displacement_r,
        W_combine, b_combine, y);

    int rows = out_size / E;                      // 65536
    int grid = rows / ROWS_PER_BC_BLOCK;          // 2048 blocks
    bcast_kernel<<<grid, 256, 0, stream>>>((const f32x4*)y, (f32x4*)d_out);
}